// Round 7
// baseline (102.032 us; speedup 1.0000x reference)
//
#include <hip/hip_runtime.h>
#include <math.h>

// Round 7: fp16 MFMA, weights pre-transposed to fp16 in d_ws by a tiny
// pre-kernel (amortized across all 1024 blocks). B-frags load directly
// global->VGPR (L1-hot, vmcnt) while A-frags come from LDS (lgkmcnt) --
// independent counters, AITER-style. 32 nodes/block, grid 1024 = 4 blocks/CU
// (round-6 was grid-capped at 2). LDS arena 15.4 KB, 5 barriers.
// Frag layouts (verified R6 pass): A[m=lane&15][k=(lane>>4)*8+j],
// B[k=(lane>>4)*8+j][n=lane&15], D: row=(lane>>4)*4+reg, col=lane&15.

typedef _Float16 h8 __attribute__((ext_vector_type(8)));
typedef float    f4 __attribute__((ext_vector_type(4)));

// ws fp16 layout (element offsets)
constexpr int WCT_O = 0;        // Wct [128][96]
constexpr int W1T_O = 12288;    // W1t [64][128]
constexpr int W2T_O = 20480;    // W2t [32][64]
constexpr int W3T_O = 22528;    // W3t [16][32]
constexpr int WS_N  = 23040;

// LDS strides (fp16 elems; byte stride %16==0)
constexpr int SVH = 104;  // V  [32][96]
constexpr int SCH = 136;  // C  [32][128]
constexpr int S1H = 72;   // H1 [32][64]
constexpr int S2H = 40;   // H2 [32][32]
constexpr int S3H = 24;   // H3 [32][16]
constexpr int H3O = 32 * S2H;   // H3 region inside sC, after H2

__global__ __launch_bounds__(256)
void cvt_weights(const float* __restrict__ Wc, const float* __restrict__ W1,
                 const float* __restrict__ W2, const float* __restrict__ W3,
                 _Float16* __restrict__ ws16)
{
    const int i = blockIdx.x * 256 + threadIdx.x;   // 0..23039
    float v;
    if (i < 12288) {                       // Wct[n][k] <- Wc[k*128+n], K=96
        const int n = i / 96, k = i - n * 96;
        v = Wc[k * 128 + n];
    } else if (i < 20480) {                // W1t, K=128
        const int j = i - 12288, n = j >> 7, k = j & 127;
        v = W1[k * 64 + n];
    } else if (i < 22528) {                // W2t, K=64
        const int j = i - 20480, n = j >> 6, k = j & 63;
        v = W2[k * 32 + n];
    } else {                               // W3t, K=32
        const int j = i - 22528, n = j >> 5, k = j & 31;
        v = W3[k * 16 + n];
    }
    ws16[i] = (_Float16)v;
}

__global__ __launch_bounds__(256, 4)
void flatnet_fused(const float* __restrict__ pgi,
                   const float* __restrict__ Wl, const float* __restrict__ bl,
                   const _Float16* __restrict__ ws16,
                   const float* __restrict__ bc, const float* __restrict__ b1,
                   const float* __restrict__ b2, const float* __restrict__ b3,
                   const float* __restrict__ W4, const float* __restrict__ b4,
                   float* __restrict__ out)
{
    __shared__ __align__(16) _Float16 sV[32 * SVH];   // V -> H1
    __shared__ __align__(16) _Float16 sC[32 * SCH];   // C -> H2,H3

    const int t    = threadIdx.x;
    const int blk  = blockIdx.x;
    const int lane = t & 63;
    const int wv   = t >> 6;        // 0..3
    const int l15  = lane & 15;
    const int lq   = lane >> 4;     // 0..3

    // ===== Phase 0: lift (3->32) fp32 + ring-group max (pre-act), leaky after =====
    // 8 threads/node: q&3 = dim-quarter, q>>2 = mirrored row-half (GT[7-r]==GT[r]).
    {
        const int ln = t >> 3;          // local node 0..31
        const int q  = t & 7;
        const int dq = (q & 3) * 8;
        const int h  = q >> 2;
        const int gn = blk * 32 + ln;
        const int b  = gn >> 10;
        const int g  = gn & 1023;
        const int gi = g >> 5, gj = g & 31;

        float w0[8], w1[8], w2[8], bb[8];
        #pragma unroll
        for (int d = 0; d < 8; ++d) {
            w0[d] = Wl[dq + d];
            w1[d] = Wl[32 + dq + d];
            w2[d] = Wl[64 + dq + d];
            bb[d] = bl[dq + d];
        }

        float gm[3][8];
        #pragma unroll
        for (int gg = 0; gg < 3; ++gg)
            #pragma unroll
            for (int d = 0; d < 8; ++d) gm[gg][d] = -INFINITY;

        constexpr int GT4[4][8] = {
            {2,2,2,2,2,2,2,2},
            {2,2,2,2,2,2,2,2},
            {2,2,1,1,1,1,2,2},
            {2,2,1,0,0,1,2,2},
        };

        const size_t rowbase = (size_t)b * 65536 + ((size_t)gi * 8) * 256 + (size_t)gj * 8;
        #pragma unroll
        for (int pi = 0; pi < 4; ++pi) {
            const int prow = h ? (7 - pi) : pi;
            const float4* src = (const float4*)(pgi + (rowbase + (size_t)prow * 256) * 3);
            float f[24];
            #pragma unroll
            for (int l = 0; l < 6; ++l) {
                const float4 v = src[l];
                f[l*4+0] = v.x; f[l*4+1] = v.y; f[l*4+2] = v.z; f[l*4+3] = v.w;
            }
            #pragma unroll
            for (int pj = 0; pj < 8; ++pj) {
                const int grp = GT4[pi][pj];
                const float x = f[pj*3], y = f[pj*3+1], z = f[pj*3+2];
                #pragma unroll
                for (int d = 0; d < 8; ++d) {
                    float v = fmaf(x, w0[d], bb[d]);
                    v = fmaf(y, w1[d], v);
                    v = fmaf(z, w2[d], v);
                    gm[grp][d] = fmaxf(gm[grp][d], v);
                }
            }
        }
        #pragma unroll
        for (int gg = 0; gg < 3; ++gg)
            #pragma unroll
            for (int d = 0; d < 8; ++d)
                gm[gg][d] = fmaxf(gm[gg][d], __shfl_xor(gm[gg][d], 4));

        if (h == 0) {
            #pragma unroll
            for (int gg = 0; gg < 3; ++gg) {
                h8 hv;
                #pragma unroll
                for (int d = 0; d < 8; ++d) {
                    const float v = gm[gg][d];
                    hv[d] = (_Float16)fmaxf(v, 0.2f * v);
                }
                *(h8*)&sV[ln*SVH + gg*32 + dq] = hv;
            }
        }
    }
    __syncthreads();

    // ===== Phase 1 (MFMA): C = leaky(V[32,96] @ Wc + bc) =====
    // wave wv -> N-tiles {2wv,2wv+1}; M-tiles 0,1; K = 3 steps.
    {
        const int nt0 = wv * 2;
        h8 Bf[2][3];
        float bcv[2];
        #pragma unroll
        for (int nn = 0; nn < 2; ++nn) {
            bcv[nn] = bc[(nt0+nn)*16 + l15];
            #pragma unroll
            for (int kq = 0; kq < 3; ++kq)
                Bf[nn][kq] = *(const h8*)&ws16[WCT_O + ((nt0+nn)*16 + l15)*96 + kq*32 + lq*8];
        }
        f4 acc[2][2];
        #pragma unroll
        for (int mt = 0; mt < 2; ++mt)
            #pragma unroll
            for (int nn = 0; nn < 2; ++nn) {
                f4 z = {bcv[nn], bcv[nn], bcv[nn], bcv[nn]};
                acc[mt][nn] = z;
            }
        #pragma unroll
        for (int mt = 0; mt < 2; ++mt) {
            #pragma unroll
            for (int kq = 0; kq < 3; ++kq) {
                const h8 Af = *(const h8*)&sV[(mt*16 + l15)*SVH + kq*32 + lq*8];
                acc[mt][0] = __builtin_amdgcn_mfma_f32_16x16x32_f16(Af, Bf[0][kq], acc[mt][0], 0, 0, 0);
                acc[mt][1] = __builtin_amdgcn_mfma_f32_16x16x32_f16(Af, Bf[1][kq], acc[mt][1], 0, 0, 0);
            }
        }
        __syncthreads();   // V reads done (C region independent, but keeps order cheap)
        #pragma unroll
        for (int mt = 0; mt < 2; ++mt)
            #pragma unroll
            for (int nn = 0; nn < 2; ++nn) {
                const int col = (nt0+nn)*16 + l15;
                #pragma unroll
                for (int r = 0; r < 4; ++r) {
                    const int row = mt*16 + lq*4 + r;
                    const float v = acc[mt][nn][r];
                    sC[row*SCH + col] = (_Float16)fmaxf(v, 0.2f * v);
                }
            }
    }
    __syncthreads();

    // ===== Phase 2 (MFMA): H1 = relu(C[32,128] @ W1 + b1) =====
    // wave wv -> N-tile wv; M-tiles 0,1; K = 4 steps.
    {
        h8 Bf[4];
        #pragma unroll
        for (int kq = 0; kq < 4; ++kq)
            Bf[kq] = *(const h8*)&ws16[W1T_O + (wv*16 + l15)*128 + kq*32 + lq*8];
        const float bv = b1[wv*16 + l15];
        f4 acc[2];
        #pragma unroll
        for (int mt = 0; mt < 2; ++mt) { f4 z = {bv,bv,bv,bv}; acc[mt] = z; }
        #pragma unroll
        for (int mt = 0; mt < 2; ++mt)
            #pragma unroll
            for (int kq = 0; kq < 4; ++kq) {
                const h8 Af = *(const h8*)&sC[(mt*16 + l15)*SCH + kq*32 + lq*8];
                acc[mt] = __builtin_amdgcn_mfma_f32_16x16x32_f16(Af, Bf[kq], acc[mt], 0, 0, 0);
            }
        __syncthreads();   // C reads done -> sV region reusable for H1
        #pragma unroll
        for (int mt = 0; mt < 2; ++mt) {
            const int col = wv*16 + l15;
            #pragma unroll
            for (int r = 0; r < 4; ++r) {
                const int row = mt*16 + lq*4 + r;
                sV[row*S1H + col] = (_Float16)fmaxf(acc[mt][r], 0.f);
            }
        }
    }
    __syncthreads();

    // ===== Phase 3 (MFMA): H2 = relu(H1[32,64] @ W2 + b2) =====
    // 4 tiles: wave wv -> (mt = wv&1, nt = wv>>1); K = 2 steps.
    {
        const int mt = wv & 1;
        const int nt = wv >> 1;
        h8 Bf[2];
        #pragma unroll
        for (int kq = 0; kq < 2; ++kq)
            Bf[kq] = *(const h8*)&ws16[W2T_O + (nt*16 + l15)*64 + kq*32 + lq*8];
        const float bv = b2[nt*16 + l15];
        f4 acc = {bv, bv, bv, bv};
        #pragma unroll
        for (int kq = 0; kq < 2; ++kq) {
            const h8 Af = *(const h8*)&sV[(mt*16 + l15)*S1H + kq*32 + lq*8];
            acc = __builtin_amdgcn_mfma_f32_16x16x32_f16(Af, Bf[kq], acc, 0, 0, 0);
        }
        __syncthreads();   // H1 reads done; C region dead -> write H2
        const int col = nt*16 + l15;
        #pragma unroll
        for (int r = 0; r < 4; ++r) {
            const int row = mt*16 + lq*4 + r;
            sC[row*S2H + col] = (_Float16)fmaxf(acc[r], 0.f);
        }
    }
    __syncthreads();

    // ===== Phase 4 (MFMA): H3 = relu(H2[32,32] @ W3 + b3) =====
    // 2 tiles: waves 0,1 -> mt = wv; single N-tile; K = 1 step.
    if (wv < 2) {
        const h8 Bf = *(const h8*)&ws16[W3T_O + l15*32 + lq*8];
        const float bv = b3[l15];
        f4 acc = {bv, bv, bv, bv};
        const h8 Af = *(const h8*)&sC[(wv*16 + l15)*S2H + lq*8];
        acc = __builtin_amdgcn_mfma_f32_16x16x32_f16(Af, Bf, acc, 0, 0, 0);
        #pragma unroll
        for (int r = 0; r < 4; ++r) {
            const int row = wv*16 + lq*4 + r;
            sC[H3O + row*S3H + l15] = (_Float16)fmaxf(acc[r], 0.f);
        }
    }
    __syncthreads();

    // ===== Phase 5: out = H3[32,16] @ W4[16,3] + b4 (fp32 VALU) =====
    if (t < 32) {
        const h8 h0 = *(const h8*)&sC[H3O + t*S3H];
        const h8 h1 = *(const h8*)&sC[H3O + t*S3H + 8];
        float a[16];
        #pragma unroll
        for (int j = 0; j < 8; ++j) { a[j] = (float)h0[j]; a[8+j] = (float)h1[j]; }
        float acc0 = b4[0], acc1 = b4[1], acc2 = b4[2];
        #pragma unroll
        for (int j = 0; j < 16; ++j) {
            acc0 = fmaf(a[j], W4[j*3+0], acc0);
            acc1 = fmaf(a[j], W4[j*3+1], acc1);
            acc2 = fmaf(a[j], W4[j*3+2], acc2);
        }
        const size_t gn = (size_t)blk * 32 + t;
        out[gn*3 + 0] = acc0;
        out[gn*3 + 1] = acc1;
        out[gn*3 + 2] = acc2;
    }
}

extern "C" void kernel_launch(void* const* d_in, const int* in_sizes, int n_in,
                              void* d_out, int out_size, void* d_ws, size_t ws_size,
                              hipStream_t stream)
{
    const float* pgi = (const float*)d_in[0];
    const float* Wl  = (const float*)d_in[1];
    const float* bl  = (const float*)d_in[2];
    const float* Wc  = (const float*)d_in[3];
    const float* bc  = (const float*)d_in[4];
    const float* W1  = (const float*)d_in[5];
    const float* b1  = (const float*)d_in[6];
    const float* W2  = (const float*)d_in[7];
    const float* b2  = (const float*)d_in[8];
    const float* W3  = (const float*)d_in[9];
    const float* b3  = (const float*)d_in[10];
    const float* W4  = (const float*)d_in[11];
    const float* b4  = (const float*)d_in[12];

    _Float16* ws16 = (_Float16*)d_ws;   // 23040 elems = 46 KB

    hipLaunchKernelGGL(cvt_weights, dim3(90), dim3(256), 0, stream,
                       Wc, W1, W2, W3, ws16);
    hipLaunchKernelGGL(flatnet_fused, dim3(1024), dim3(256), 0, stream,
                       pgi, Wl, bl, ws16, bc, b1, b2, b3, W4, b4,
                       (float*)d_out);
}

// Round 8
// 101.293 us; speedup vs baseline: 1.0073x; 1.0073x over previous
//
#include <hip/hip_runtime.h>
#include <math.h>

// Round 8: single-pass fp16 MFMA with frag-linear weight prefetch.
// - cvt_weights pre-kernel writes ws16 in FRAG-LINEAR order: frag f occupies
//   ws16[f*512 + lane*8 .. +7], so a wave's B-frag load is one coalesced 1KB
//   ds-free global b128 (vmcnt), issued ONE PHASE EARLY into registers.
// - 32 nodes/block, grid 1024 (4 blocks/CU), LDS 15.4KB, 4 barriers.
// - P4+P5 fused: H3 stays in fp32 regs; out = shfl_xor reduction over the
//   16-lane MFMA D columns. No H3 LDS region, no final barrier.
// Frag layouts (verified R6/R7 pass): A[m=lane&15][k=(lane>>4)*8+j],
// B[k=(lane>>4)*8+j][n=lane&15], D: row=(lane>>4)*4+reg, col=lane&15.

typedef _Float16 h8 __attribute__((ext_vector_type(8)));
typedef float    f4 __attribute__((ext_vector_type(4)));

// LDS strides (fp16 elems; byte stride %16==0)
constexpr int SVH = 104;  // V  [32][96]   -> H1 [32][64] (S1H)
constexpr int SCH = 136;  // C  [32][128]  -> H2 [32][32] (S2H)
constexpr int S1H = 72;
constexpr int S2H = 40;

// frag-linear bases (frag ids): P1: 24 (4wv x 2nn x 3kq), P2: 16 (4wv x 4kq),
// P3: 8 (4wv x 2kq, B dup per nt), P4: 2 (dup per wave)
constexpr int P1B = 0, P2B = 24, P3B = 40, P4B = 48;   // 50 frags * 512 fp16 = 50KB

__global__ __launch_bounds__(256)
void cvt_weights(const float* __restrict__ Wc, const float* __restrict__ W1,
                 const float* __restrict__ W2, const float* __restrict__ W3,
                 _Float16* __restrict__ ws16)
{
    const int i = blockIdx.x * 256 + threadIdx.x;   // 0..25599
    const int fid  = i >> 9;
    const int r    = i & 511;
    const int lane = r >> 3, j = r & 7;
    const int l15  = lane & 15, lq = lane >> 4;
    const int klo  = lq * 8 + j;
    float v;
    if (fid < 24) {                               // P1: B[k][n] from Wc[96,128]
        const int wv = fid / 6, q = fid % 6, nn = q / 3, kq = q % 3;
        v = Wc[(kq * 32 + klo) * 128 + (wv * 2 + nn) * 16 + l15];
    } else if (fid < 40) {                        // P2: W1[128,64]
        const int f2 = fid - 24, wv = f2 >> 2, kq = f2 & 3;
        v = W1[(kq * 32 + klo) * 64 + wv * 16 + l15];
    } else if (fid < 48) {                        // P3: W2[64,32]
        const int f3 = fid - 40, wv = f3 >> 1, kq = f3 & 1, nt = wv >> 1;
        v = W2[(kq * 32 + klo) * 32 + nt * 16 + l15];
    } else {                                      // P4: W3[32,16]
        v = W3[klo * 16 + l15];
    }
    ws16[i] = (_Float16)v;
}

__global__ __launch_bounds__(256, 4)
void flatnet_fused(const float* __restrict__ pgi,
                   const float* __restrict__ Wl, const float* __restrict__ bl,
                   const _Float16* __restrict__ ws16,
                   const float* __restrict__ bc, const float* __restrict__ b1,
                   const float* __restrict__ b2, const float* __restrict__ b3,
                   const float* __restrict__ W4, const float* __restrict__ b4,
                   float* __restrict__ out)
{
    __shared__ __align__(16) _Float16 sV[32 * SVH];   // V -> H1
    __shared__ __align__(16) _Float16 sC[32 * SCH];   // C -> H2

    const int t    = threadIdx.x;
    const int blk  = blockIdx.x;
    const int lane = t & 63;
    const int wv   = t >> 6;        // 0..3
    const int l15  = lane & 15;
    const int lq   = lane >> 4;     // 0..3

    // -- prefetch P1 B-frags + bias (consumed after barrier 1; latency hidden by lift)
    h8 Bf1[2][3];
    #pragma unroll
    for (int nn = 0; nn < 2; ++nn)
        #pragma unroll
        for (int kq = 0; kq < 3; ++kq)
            Bf1[nn][kq] = *(const h8*)&ws16[(P1B + wv*6 + nn*3 + kq) * 512 + lane * 8];
    float bcv[2];
    bcv[0] = bc[(wv*2 + 0)*16 + l15];
    bcv[1] = bc[(wv*2 + 1)*16 + l15];

    // ===== Phase 0: lift (3->32) fp32 + ring-group max (pre-act), leaky after =====
    // 8 threads/node: q&3 = dim-quarter, q>>2 = mirrored row-half (GT[7-r]==GT[r]).
    {
        const int ln = t >> 3;          // local node 0..31
        const int q  = t & 7;
        const int dq = (q & 3) * 8;
        const int h  = q >> 2;
        const int gn = blk * 32 + ln;
        const int b  = gn >> 10;
        const int g  = gn & 1023;
        const int gi = g >> 5, gj = g & 31;

        float w0[8], w1[8], w2[8], bb[8];
        #pragma unroll
        for (int d = 0; d < 8; ++d) {
            w0[d] = Wl[dq + d];
            w1[d] = Wl[32 + dq + d];
            w2[d] = Wl[64 + dq + d];
            bb[d] = bl[dq + d];
        }

        float gm[3][8];
        #pragma unroll
        for (int gg = 0; gg < 3; ++gg)
            #pragma unroll
            for (int d = 0; d < 8; ++d) gm[gg][d] = -INFINITY;

        constexpr int GT4[4][8] = {
            {2,2,2,2,2,2,2,2},
            {2,2,2,2,2,2,2,2},
            {2,2,1,1,1,1,2,2},
            {2,2,1,0,0,1,2,2},
        };

        const size_t rowbase = (size_t)b * 65536 + ((size_t)gi * 8) * 256 + (size_t)gj * 8;
        #pragma unroll
        for (int pi = 0; pi < 4; ++pi) {
            const int prow = h ? (7 - pi) : pi;
            const float4* src = (const float4*)(pgi + (rowbase + (size_t)prow * 256) * 3);
            float f[24];
            #pragma unroll
            for (int l = 0; l < 6; ++l) {
                const float4 v = src[l];
                f[l*4+0] = v.x; f[l*4+1] = v.y; f[l*4+2] = v.z; f[l*4+3] = v.w;
            }
            #pragma unroll
            for (int pj = 0; pj < 8; ++pj) {
                const int grp = GT4[pi][pj];
                const float x = f[pj*3], y = f[pj*3+1], z = f[pj*3+2];
                #pragma unroll
                for (int d = 0; d < 8; ++d) {
                    float v = fmaf(x, w0[d], bb[d]);
                    v = fmaf(y, w1[d], v);
                    v = fmaf(z, w2[d], v);
                    gm[grp][d] = fmaxf(gm[grp][d], v);
                }
            }
        }
        #pragma unroll
        for (int gg = 0; gg < 3; ++gg)
            #pragma unroll
            for (int d = 0; d < 8; ++d)
                gm[gg][d] = fmaxf(gm[gg][d], __shfl_xor(gm[gg][d], 4));

        if (h == 0) {
            #pragma unroll
            for (int gg = 0; gg < 3; ++gg) {
                h8 hv;
                #pragma unroll
                for (int d = 0; d < 8; ++d) {
                    const float v = gm[gg][d];
                    hv[d] = (_Float16)fmaxf(v, 0.2f * v);
                }
                *(h8*)&sV[ln*SVH + gg*32 + dq] = hv;
            }
        }
    }
    __syncthreads();   // barrier 1: V ready

    // -- prefetch P2 B-frags + bias (consumed after barrier 2)
    h8 Bf2[4];
    #pragma unroll
    for (int kq = 0; kq < 4; ++kq)
        Bf2[kq] = *(const h8*)&ws16[(P2B + wv*4 + kq) * 512 + lane * 8];
    const float b1v = b1[wv*16 + l15];

    // ===== Phase 1 (MFMA): C = leaky(V[32,96] @ Wc + bc) =====
    {
        f4 acc[2][2];
        #pragma unroll
        for (int mt = 0; mt < 2; ++mt)
            #pragma unroll
            for (int nn = 0; nn < 2; ++nn) {
                f4 z = {bcv[nn], bcv[nn], bcv[nn], bcv[nn]};
                acc[mt][nn] = z;
            }
        #pragma unroll
        for (int mt = 0; mt < 2; ++mt)
            #pragma unroll
            for (int kq = 0; kq < 3; ++kq) {
                const h8 Af = *(const h8*)&sV[(mt*16 + l15)*SVH + kq*32 + lq*8];
                acc[mt][0] = __builtin_amdgcn_mfma_f32_16x16x32_f16(Af, Bf1[0][kq], acc[mt][0], 0, 0, 0);
                acc[mt][1] = __builtin_amdgcn_mfma_f32_16x16x32_f16(Af, Bf1[1][kq], acc[mt][1], 0, 0, 0);
            }
        // epilogue straight into sC (disjoint from sV -> no barrier needed)
        #pragma unroll
        for (int mt = 0; mt < 2; ++mt)
            #pragma unroll
            for (int nn = 0; nn < 2; ++nn) {
                const int col = (wv*2 + nn)*16 + l15;
                #pragma unroll
                for (int r = 0; r < 4; ++r) {
                    const int row = mt*16 + lq*4 + r;
                    const float v = acc[mt][nn][r];
                    sC[row*SCH + col] = (_Float16)fmaxf(v, 0.2f * v);
                }
            }
    }
    __syncthreads();   // barrier 2: C ready (and all V reads done)

    // -- prefetch P3/P4 B-frags + biases + W4 (consumed after barriers 3/4)
    h8 Bf3[2];
    #pragma unroll
    for (int kq = 0; kq < 2; ++kq)
        Bf3[kq] = *(const h8*)&ws16[(P3B + wv*2 + kq) * 512 + lane * 8];
    const h8 Bf4 = *(const h8*)&ws16[(P4B + (wv & 1)) * 512 + lane * 8];
    const float b2v = b2[(wv >> 1)*16 + l15];
    const float b3v = b3[l15];
    float w4c[3];
    #pragma unroll
    for (int c = 0; c < 3; ++c) w4c[c] = W4[l15*3 + c];

    // ===== Phase 2 (MFMA): H1 = relu(C[32,128] @ W1 + b1) =====
    {
        f4 acc[2];
        #pragma unroll
        for (int mt = 0; mt < 2; ++mt) { f4 z = {b1v,b1v,b1v,b1v}; acc[mt] = z; }
        #pragma unroll
        for (int mt = 0; mt < 2; ++mt)
            #pragma unroll
            for (int kq = 0; kq < 4; ++kq) {
                const h8 Af = *(const h8*)&sC[(mt*16 + l15)*SCH + kq*32 + lq*8];
                acc[mt] = __builtin_amdgcn_mfma_f32_16x16x32_f16(Af, Bf2[kq], acc[mt], 0, 0, 0);
            }
        // epilogue into sV (H1): V reads all completed before barrier 2
        #pragma unroll
        for (int mt = 0; mt < 2; ++mt) {
            const int col = wv*16 + l15;
            #pragma unroll
            for (int r = 0; r < 4; ++r) {
                const int row = mt*16 + lq*4 + r;
                sV[row*S1H + col] = (_Float16)fmaxf(acc[mt][r], 0.f);
            }
        }
    }
    __syncthreads();   // barrier 3: H1 ready (and all C reads done)

    // ===== Phase 3 (MFMA): H2 = relu(H1[32,64] @ W2 + b2) =====
    {
        const int mt = wv & 1;
        const int nt = wv >> 1;
        f4 acc = {b2v, b2v, b2v, b2v};
        #pragma unroll
        for (int kq = 0; kq < 2; ++kq) {
            const h8 Af = *(const h8*)&sV[(mt*16 + l15)*S1H + kq*32 + lq*8];
            acc = __builtin_amdgcn_mfma_f32_16x16x32_f16(Af, Bf3[kq], acc, 0, 0, 0);
        }
        // epilogue into sC (H2 region): C reads done before barrier 3
        const int col = nt*16 + l15;
        #pragma unroll
        for (int r = 0; r < 4; ++r) {
            const int row = mt*16 + lq*4 + r;
            sC[row*S2H + col] = (_Float16)fmaxf(acc[r], 0.f);
        }
    }
    __syncthreads();   // barrier 4: H2 ready

    // ===== Phase 4+5 fused: H3 = relu(H2 @ W3 + b3); out = H3 @ W4 + b4 =====
    // waves 0,1 -> M-tile wv. H3 stays in fp32 regs (D-layout); the K=16
    // contraction with W4 is a shfl_xor reduction over the 16-lane column group.
    if (wv < 2) {
        f4 acc = {b3v, b3v, b3v, b3v};
        const h8 Af = *(const h8*)&sC[(wv*16 + l15)*S2H + lq*8];
        acc = __builtin_amdgcn_mfma_f32_16x16x32_f16(Af, Bf4, acc, 0, 0, 0);
        #pragma unroll
        for (int r = 0; r < 4; ++r) {
            const float h3 = fmaxf(acc[r], 0.f);    // H3[row][l15], row = wv*16+lq*4+r
            #pragma unroll
            for (int c = 0; c < 3; ++c) {
                float p = h3 * w4c[c];
                p += __shfl_xor(p, 1);
                p += __shfl_xor(p, 2);
                p += __shfl_xor(p, 4);
                p += __shfl_xor(p, 8);
                if (l15 == c) {
                    const int gn = blk*32 + wv*16 + lq*4 + r;
                    out[gn*3 + c] = p + b4[c];
                }
            }
        }
    }
}

extern "C" void kernel_launch(void* const* d_in, const int* in_sizes, int n_in,
                              void* d_out, int out_size, void* d_ws, size_t ws_size,
                              hipStream_t stream)
{
    const float* pgi = (const float*)d_in[0];
    const float* Wl  = (const float*)d_in[1];
    const float* bl  = (const float*)d_in[2];
    const float* Wc  = (const float*)d_in[3];
    const float* bc  = (const float*)d_in[4];
    const float* W1  = (const float*)d_in[5];
    const float* b1  = (const float*)d_in[6];
    const float* W2  = (const float*)d_in[7];
    const float* b2  = (const float*)d_in[8];
    const float* W3  = (const float*)d_in[9];
    const float* b3  = (const float*)d_in[10];
    const float* W4  = (const float*)d_in[11];
    const float* b4  = (const float*)d_in[12];

    _Float16* ws16 = (_Float16*)d_ws;   // 50 frags * 512 fp16 = 51200 B

    hipLaunchKernelGGL(cvt_weights, dim3(100), dim3(256), 0, stream,
                       Wc, W1, W2, W3, ws16);
    hipLaunchKernelGGL(flatnet_fused, dim3(1024), dim3(256), 0, stream,
                       pgi, Wl, bl, ws16, bc, b1, b2, b3, W4, b4,
                       (float*)d_out);
}

// Round 9
// 99.520 us; speedup vs baseline: 1.0252x; 1.0178x over previous
//
#include <hip/hip_runtime.h>
#include <math.h>

// Round 9: single-kernel fp16 MFMA. The cvt_weights pre-kernel is gone --
// each wave gathers its 13 B-frags straight from the fp32 weights (8 strided
// dword loads + v_cvt per frag), issued one phase early so latency hides
// under the preceding phase's work (same schedule as R8's prefetches):
//   Bf1 before lift, Bf2 after barrier 1, Bf3/Bf4 after barrier 2.
// 32 nodes/block, grid 1024 (4 blocks/CU), LDS 15.4KB, 4 barriers.
// P4+P5 fused via shfl_xor reduction (H3 never touches LDS).
// Frag layouts (verified R6/R7/R8 pass): A[m=lane&15][k=(lane>>4)*8+j],
// B[k=(lane>>4)*8+j][n=lane&15], D: row=(lane>>4)*4+reg, col=lane&15.

typedef _Float16 h8 __attribute__((ext_vector_type(8)));
typedef float    f4 __attribute__((ext_vector_type(4)));

// LDS strides (fp16 elems; byte stride %16==0)
constexpr int SVH = 104;  // V  [32][96]   -> H1 [32][64] (S1H)
constexpr int SCH = 136;  // C  [32][128]  -> H2 [32][32] (S2H)
constexpr int S1H = 72;
constexpr int S2H = 40;

// gather one B-frag: lane provides k-octet base k0 = (lane>>4)*8 (+32*kq) and
// column n; W is row-major [K][N].
__device__ __forceinline__ h8 bfrag(const float* __restrict__ W, int N, int k0, int n)
{
    h8 r;
    #pragma unroll
    for (int j = 0; j < 8; ++j)
        r[j] = (_Float16)W[(k0 + j) * N + n];
    return r;
}

__global__ __launch_bounds__(256, 4)
void flatnet_fused(const float* __restrict__ pgi,
                   const float* __restrict__ Wl, const float* __restrict__ bl,
                   const float* __restrict__ Wc, const float* __restrict__ bc,
                   const float* __restrict__ W1, const float* __restrict__ b1,
                   const float* __restrict__ W2, const float* __restrict__ b2,
                   const float* __restrict__ W3, const float* __restrict__ b3,
                   const float* __restrict__ W4, const float* __restrict__ b4,
                   float* __restrict__ out)
{
    __shared__ __align__(16) _Float16 sV[32 * SVH];   // V -> H1
    __shared__ __align__(16) _Float16 sC[32 * SCH];   // C -> H2

    const int t    = threadIdx.x;
    const int blk  = blockIdx.x;
    const int lane = t & 63;
    const int wv   = t >> 6;        // 0..3
    const int l15  = lane & 15;
    const int lq   = lane >> 4;     // 0..3
    const int k8   = lq * 8;        // lane's k-octet base

    // -- build P1 B-frags + bias now (consumed after barrier 1; hidden by lift)
    h8 Bf1[2][3];
    #pragma unroll
    for (int nn = 0; nn < 2; ++nn)
        #pragma unroll
        for (int kq = 0; kq < 3; ++kq)
            Bf1[nn][kq] = bfrag(Wc, 128, kq*32 + k8, (wv*2 + nn)*16 + l15);
    float bcv[2];
    bcv[0] = bc[(wv*2 + 0)*16 + l15];
    bcv[1] = bc[(wv*2 + 1)*16 + l15];

    // ===== Phase 0: lift (3->32) fp32 + ring-group max (pre-act), leaky after =====
    // 8 threads/node: q&3 = dim-quarter, q>>2 = mirrored row-half (GT[7-r]==GT[r]).
    {
        const int ln = t >> 3;          // local node 0..31
        const int q  = t & 7;
        const int dq = (q & 3) * 8;
        const int h  = q >> 2;
        const int gn = blk * 32 + ln;
        const int b  = gn >> 10;
        const int g  = gn & 1023;
        const int gi = g >> 5, gj = g & 31;

        float w0[8], w1[8], w2[8], bb[8];
        #pragma unroll
        for (int d = 0; d < 8; ++d) {
            w0[d] = Wl[dq + d];
            w1[d] = Wl[32 + dq + d];
            w2[d] = Wl[64 + dq + d];
            bb[d] = bl[dq + d];
        }

        float gm[3][8];
        #pragma unroll
        for (int gg = 0; gg < 3; ++gg)
            #pragma unroll
            for (int d = 0; d < 8; ++d) gm[gg][d] = -INFINITY;

        constexpr int GT4[4][8] = {
            {2,2,2,2,2,2,2,2},
            {2,2,2,2,2,2,2,2},
            {2,2,1,1,1,1,2,2},
            {2,2,1,0,0,1,2,2},
        };

        const size_t rowbase = (size_t)b * 65536 + ((size_t)gi * 8) * 256 + (size_t)gj * 8;
        #pragma unroll
        for (int pi = 0; pi < 4; ++pi) {
            const int prow = h ? (7 - pi) : pi;
            const float4* src = (const float4*)(pgi + (rowbase + (size_t)prow * 256) * 3);
            float f[24];
            #pragma unroll
            for (int l = 0; l < 6; ++l) {
                const float4 v = src[l];
                f[l*4+0] = v.x; f[l*4+1] = v.y; f[l*4+2] = v.z; f[l*4+3] = v.w;
            }
            #pragma unroll
            for (int pj = 0; pj < 8; ++pj) {
                const int grp = GT4[pi][pj];
                const float x = f[pj*3], y = f[pj*3+1], z = f[pj*3+2];
                #pragma unroll
                for (int d = 0; d < 8; ++d) {
                    float v = fmaf(x, w0[d], bb[d]);
                    v = fmaf(y, w1[d], v);
                    v = fmaf(z, w2[d], v);
                    gm[grp][d] = fmaxf(gm[grp][d], v);
                }
            }
        }
        #pragma unroll
        for (int gg = 0; gg < 3; ++gg)
            #pragma unroll
            for (int d = 0; d < 8; ++d)
                gm[gg][d] = fmaxf(gm[gg][d], __shfl_xor(gm[gg][d], 4));

        if (h == 0) {
            #pragma unroll
            for (int gg = 0; gg < 3; ++gg) {
                h8 hv;
                #pragma unroll
                for (int d = 0; d < 8; ++d) {
                    const float v = gm[gg][d];
                    hv[d] = (_Float16)fmaxf(v, 0.2f * v);
                }
                *(h8*)&sV[ln*SVH + gg*32 + dq] = hv;
            }
        }
    }
    __syncthreads();   // barrier 1: V ready

    // -- build P2 B-frags + bias (consumed after barrier 2; hidden by phase 1)
    h8 Bf2[4];
    #pragma unroll
    for (int kq = 0; kq < 4; ++kq)
        Bf2[kq] = bfrag(W1, 64, kq*32 + k8, wv*16 + l15);
    const float b1v = b1[wv*16 + l15];

    // ===== Phase 1 (MFMA): C = leaky(V[32,96] @ Wc + bc) =====
    {
        f4 acc[2][2];
        #pragma unroll
        for (int mt = 0; mt < 2; ++mt)
            #pragma unroll
            for (int nn = 0; nn < 2; ++nn) {
                f4 z = {bcv[nn], bcv[nn], bcv[nn], bcv[nn]};
                acc[mt][nn] = z;
            }
        #pragma unroll
        for (int mt = 0; mt < 2; ++mt)
            #pragma unroll
            for (int kq = 0; kq < 3; ++kq) {
                const h8 Af = *(const h8*)&sV[(mt*16 + l15)*SVH + kq*32 + lq*8];
                acc[mt][0] = __builtin_amdgcn_mfma_f32_16x16x32_f16(Af, Bf1[0][kq], acc[mt][0], 0, 0, 0);
                acc[mt][1] = __builtin_amdgcn_mfma_f32_16x16x32_f16(Af, Bf1[1][kq], acc[mt][1], 0, 0, 0);
            }
        // epilogue straight into sC (disjoint from sV -> no extra barrier)
        #pragma unroll
        for (int mt = 0; mt < 2; ++mt)
            #pragma unroll
            for (int nn = 0; nn < 2; ++nn) {
                const int col = (wv*2 + nn)*16 + l15;
                #pragma unroll
                for (int r = 0; r < 4; ++r) {
                    const int row = mt*16 + lq*4 + r;
                    const float v = acc[mt][nn][r];
                    sC[row*SCH + col] = (_Float16)fmaxf(v, 0.2f * v);
                }
            }
    }
    __syncthreads();   // barrier 2: C ready (and all V reads done)

    // -- build P3/P4 B-frags + biases + W4 (consumed after barriers 3/4)
    h8 Bf3[2];
    #pragma unroll
    for (int kq = 0; kq < 2; ++kq)
        Bf3[kq] = bfrag(W2, 32, kq*32 + k8, (wv >> 1)*16 + l15);
    const h8 Bf4 = bfrag(W3, 16, k8, l15);
    const float b2v = b2[(wv >> 1)*16 + l15];
    const float b3v = b3[l15];
    float w4c[3];
    #pragma unroll
    for (int c = 0; c < 3; ++c) w4c[c] = W4[l15*3 + c];

    // ===== Phase 2 (MFMA): H1 = relu(C[32,128] @ W1 + b1) =====
    {
        f4 acc[2];
        #pragma unroll
        for (int mt = 0; mt < 2; ++mt) { f4 z = {b1v,b1v,b1v,b1v}; acc[mt] = z; }
        #pragma unroll
        for (int mt = 0; mt < 2; ++mt)
            #pragma unroll
            for (int kq = 0; kq < 4; ++kq) {
                const h8 Af = *(const h8*)&sC[(mt*16 + l15)*SCH + kq*32 + lq*8];
                acc[mt] = __builtin_amdgcn_mfma_f32_16x16x32_f16(Af, Bf2[kq], acc[mt], 0, 0, 0);
            }
        // epilogue into sV (H1): V reads all completed before barrier 2
        #pragma unroll
        for (int mt = 0; mt < 2; ++mt) {
            const int col = wv*16 + l15;
            #pragma unroll
            for (int r = 0; r < 4; ++r) {
                const int row = mt*16 + lq*4 + r;
                sV[row*S1H + col] = (_Float16)fmaxf(acc[mt][r], 0.f);
            }
        }
    }
    __syncthreads();   // barrier 3: H1 ready (and all C reads done)

    // ===== Phase 3 (MFMA): H2 = relu(H1[32,64] @ W2 + b2) =====
    {
        const int mt = wv & 1;
        const int nt = wv >> 1;
        f4 acc = {b2v, b2v, b2v, b2v};
        #pragma unroll
        for (int kq = 0; kq < 2; ++kq) {
            const h8 Af = *(const h8*)&sV[(mt*16 + l15)*S1H + kq*32 + lq*8];
            acc = __builtin_amdgcn_mfma_f32_16x16x32_f16(Af, Bf3[kq], acc, 0, 0, 0);
        }
        // epilogue into sC (H2 region): C reads done before barrier 3
        const int col = nt*16 + l15;
        #pragma unroll
        for (int r = 0; r < 4; ++r) {
            const int row = mt*16 + lq*4 + r;
            sC[row*S2H + col] = (_Float16)fmaxf(acc[r], 0.f);
        }
    }
    __syncthreads();   // barrier 4: H2 ready

    // ===== Phase 4+5 fused: H3 = relu(H2 @ W3 + b3); out = H3 @ W4 + b4 =====
    // waves 0,1 -> M-tile wv. H3 stays in fp32 regs (D-layout); the K=16
    // contraction with W4 is a shfl_xor reduction over the 16-lane column group.
    if (wv < 2) {
        f4 acc = {b3v, b3v, b3v, b3v};
        const h8 Af = *(const h8*)&sC[(wv*16 + l15)*S2H + lq*8];
        acc = __builtin_amdgcn_mfma_f32_16x16x32_f16(Af, Bf4, acc, 0, 0, 0);
        #pragma unroll
        for (int r = 0; r < 4; ++r) {
            const float h3 = fmaxf(acc[r], 0.f);    // H3[row][l15], row = wv*16+lq*4+r
            #pragma unroll
            for (int c = 0; c < 3; ++c) {
                float p = h3 * w4c[c];
                p += __shfl_xor(p, 1);
                p += __shfl_xor(p, 2);
                p += __shfl_xor(p, 4);
                p += __shfl_xor(p, 8);
                if (l15 == c) {
                    const int gn = blk*32 + wv*16 + lq*4 + r;
                    out[gn*3 + c] = p + b4[c];
                }
            }
        }
    }
}

extern "C" void kernel_launch(void* const* d_in, const int* in_sizes, int n_in,
                              void* d_out, int out_size, void* d_ws, size_t ws_size,
                              hipStream_t stream)
{
    const float* pgi = (const float*)d_in[0];
    const float* Wl  = (const float*)d_in[1];
    const float* bl  = (const float*)d_in[2];
    const float* Wc  = (const float*)d_in[3];
    const float* bc  = (const float*)d_in[4];
    const float* W1  = (const float*)d_in[5];
    const float* b1  = (const float*)d_in[6];
    const float* W2  = (const float*)d_in[7];
    const float* b2  = (const float*)d_in[8];
    const float* W3  = (const float*)d_in[9];
    const float* b3  = (const float*)d_in[10];
    const float* W4  = (const float*)d_in[11];
    const float* b4  = (const float*)d_in[12];

    hipLaunchKernelGGL(flatnet_fused, dim3(1024), dim3(256), 0, stream,
                       pgi, Wl, bl, Wc, bc, W1, b1, W2, b2, W3, b3, W4, b4,
                       (float*)d_out);
}

// Round 11
// 98.941 us; speedup vs baseline: 1.0312x; 1.0058x over previous
//
#include <hip/hip_runtime.h>
#include <math.h>

// Round 11: R9 + packed-fp16 lift, now with clang-native _Float16 vectors
// (ROCm 7.2's __hmax2 overload is broken on gfx950 -- R10 compile failure).
// Vector ops on ext_vector_type(2) _Float16 emit v_pk_fma_f16 / v_pk_max_f16.
// Everything else identical to R9 (single kernel, inline B-frag gathers one
// phase early, 32 nodes/block, grid 1024, 4 barriers, P4+P5 shfl-fused).
// Frag layouts (verified R6-R9 pass): A[m=lane&15][k=(lane>>4)*8+j],
// B[k=(lane>>4)*8+j][n=lane&15], D: row=(lane>>4)*4+reg, col=lane&15.

typedef _Float16 h8 __attribute__((ext_vector_type(8)));
typedef _Float16 h2 __attribute__((ext_vector_type(2)));
typedef float    f4 __attribute__((ext_vector_type(4)));

// LDS strides (fp16 elems; byte stride %16==0)
constexpr int SVH = 104;  // V  [32][96]   -> H1 [32][64] (S1H)
constexpr int SCH = 136;  // C  [32][128]  -> H2 [32][32] (S2H)
constexpr int S1H = 72;
constexpr int S2H = 40;

__device__ __forceinline__ h8 bfrag(const float* __restrict__ W, int N, int k0, int n)
{
    h8 r;
    #pragma unroll
    for (int j = 0; j < 8; ++j)
        r[j] = (_Float16)W[(k0 + j) * N + n];
    return r;
}

__device__ __forceinline__ h2 h2max_x4(h2 a) {   // elementwise max with lane^4
    int b;
    __builtin_memcpy(&b, &a, 4);
    b = __shfl_xor(b, 4);
    h2 o;
    __builtin_memcpy(&o, &b, 4);
    return __builtin_elementwise_max(a, o);
}

__global__ __launch_bounds__(256, 4)
void flatnet_fused(const float* __restrict__ pgi,
                   const float* __restrict__ Wl, const float* __restrict__ bl,
                   const float* __restrict__ Wc, const float* __restrict__ bc,
                   const float* __restrict__ W1, const float* __restrict__ b1,
                   const float* __restrict__ W2, const float* __restrict__ b2,
                   const float* __restrict__ W3, const float* __restrict__ b3,
                   const float* __restrict__ W4, const float* __restrict__ b4,
                   float* __restrict__ out)
{
    __shared__ __align__(16) _Float16 sV[32 * SVH];   // V -> H1
    __shared__ __align__(16) _Float16 sC[32 * SCH];   // C -> H2

    const int t    = threadIdx.x;
    const int blk  = blockIdx.x;
    const int lane = t & 63;
    const int wv   = t >> 6;        // 0..3
    const int l15  = lane & 15;
    const int lq   = lane >> 4;     // 0..3
    const int k8   = lq * 8;

    // -- build P1 B-frags + bias now (consumed after barrier 1; hidden by lift)
    h8 Bf1[2][3];
    #pragma unroll
    for (int nn = 0; nn < 2; ++nn)
        #pragma unroll
        for (int kq = 0; kq < 3; ++kq)
            Bf1[nn][kq] = bfrag(Wc, 128, kq*32 + k8, (wv*2 + nn)*16 + l15);
    float bcv[2];
    bcv[0] = bc[(wv*2 + 0)*16 + l15];
    bcv[1] = bc[(wv*2 + 1)*16 + l15];

    // ===== Phase 0: packed-fp16 lift (3->32) + ring-group max, leaky after =====
    // 8 threads/node: q&3 = dim-quarter (4 h2 pairs), q>>2 = mirrored row-half
    // (GT[7-r]==GT[r]).
    {
        const int ln = t >> 3;          // local node 0..31
        const int q  = t & 7;
        const int dq = (q & 3) * 8;
        const int h  = q >> 2;
        const int gn = blk * 32 + ln;
        const int b  = gn >> 10;
        const int g  = gn & 1023;
        const int gi = g >> 5, gj = g & 31;

        h2 w0p[4], w1p[4], w2p[4], bbp[4];
        #pragma unroll
        for (int d2 = 0; d2 < 4; ++d2) {
            const int dd = dq + d2*2;
            w0p[d2] = h2{(_Float16)Wl[dd],      (_Float16)Wl[dd + 1]};
            w1p[d2] = h2{(_Float16)Wl[32 + dd], (_Float16)Wl[32 + dd + 1]};
            w2p[d2] = h2{(_Float16)Wl[64 + dd], (_Float16)Wl[64 + dd + 1]};
            bbp[d2] = h2{(_Float16)bl[dd],      (_Float16)bl[dd + 1]};
        }

        const h2 ninf2 = h2{(_Float16)-65504.f, (_Float16)-65504.f};
        h2 gm[3][4];
        #pragma unroll
        for (int gg = 0; gg < 3; ++gg)
            #pragma unroll
            for (int d2 = 0; d2 < 4; ++d2) gm[gg][d2] = ninf2;

        constexpr int GT4[4][8] = {
            {2,2,2,2,2,2,2,2},
            {2,2,2,2,2,2,2,2},
            {2,2,1,1,1,1,2,2},
            {2,2,1,0,0,1,2,2},
        };

        const size_t rowbase = (size_t)b * 65536 + ((size_t)gi * 8) * 256 + (size_t)gj * 8;
        #pragma unroll
        for (int pi = 0; pi < 4; ++pi) {
            const int prow = h ? (7 - pi) : pi;
            const float4* src = (const float4*)(pgi + (rowbase + (size_t)prow * 256) * 3);
            float f[24];
            #pragma unroll
            for (int l = 0; l < 6; ++l) {
                const float4 v = src[l];
                f[l*4+0] = v.x; f[l*4+1] = v.y; f[l*4+2] = v.z; f[l*4+3] = v.w;
            }
            #pragma unroll
            for (int pj = 0; pj < 8; ++pj) {
                const int grp = GT4[pi][pj];
                const _Float16 x = (_Float16)f[pj*3];
                const _Float16 y = (_Float16)f[pj*3+1];
                const _Float16 z = (_Float16)f[pj*3+2];
                #pragma unroll
                for (int d2 = 0; d2 < 4; ++d2) {
                    h2 v = x * w0p[d2] + bbp[d2];     // v_pk_fma_f16
                    v = y * w1p[d2] + v;
                    v = z * w2p[d2] + v;
                    gm[grp][d2] = __builtin_elementwise_max(gm[grp][d2], v);
                }
            }
        }
        // combine mirrored row-halves (t and t^4 same wave), then leaky + store
        #pragma unroll
        for (int gg = 0; gg < 3; ++gg)
            #pragma unroll
            for (int d2 = 0; d2 < 4; ++d2)
                gm[gg][d2] = h2max_x4(gm[gg][d2]);

        if (h == 0) {
            const _Float16 c02 = (_Float16)0.2f;
            #pragma unroll
            for (int gg = 0; gg < 3; ++gg) {
                union { h8 v; h2 p[4]; } u;
                #pragma unroll
                for (int d2 = 0; d2 < 4; ++d2) {
                    const h2 g2 = gm[gg][d2];
                    u.p[d2] = __builtin_elementwise_max(g2, g2 * c02);   // leaky 0.2
                }
                *(h8*)&sV[ln*SVH + gg*32 + dq] = u.v;
            }
        }
    }
    __syncthreads();   // barrier 1: V ready

    // -- build P2 B-frags + bias (consumed after barrier 2; hidden by phase 1)
    h8 Bf2[4];
    #pragma unroll
    for (int kq = 0; kq < 4; ++kq)
        Bf2[kq] = bfrag(W1, 64, kq*32 + k8, wv*16 + l15);
    const float b1v = b1[wv*16 + l15];

    // ===== Phase 1 (MFMA): C = leaky(V[32,96] @ Wc + bc) =====
    {
        f4 acc[2][2];
        #pragma unroll
        for (int mt = 0; mt < 2; ++mt)
            #pragma unroll
            for (int nn = 0; nn < 2; ++nn) {
                f4 z = {bcv[nn], bcv[nn], bcv[nn], bcv[nn]};
                acc[mt][nn] = z;
            }
        #pragma unroll
        for (int mt = 0; mt < 2; ++mt)
            #pragma unroll
            for (int kq = 0; kq < 3; ++kq) {
                const h8 Af = *(const h8*)&sV[(mt*16 + l15)*SVH + kq*32 + lq*8];
                acc[mt][0] = __builtin_amdgcn_mfma_f32_16x16x32_f16(Af, Bf1[0][kq], acc[mt][0], 0, 0, 0);
                acc[mt][1] = __builtin_amdgcn_mfma_f32_16x16x32_f16(Af, Bf1[1][kq], acc[mt][1], 0, 0, 0);
            }
        // epilogue straight into sC (disjoint from sV -> no extra barrier)
        #pragma unroll
        for (int mt = 0; mt < 2; ++mt)
            #pragma unroll
            for (int nn = 0; nn < 2; ++nn) {
                const int col = (wv*2 + nn)*16 + l15;
                #pragma unroll
                for (int r = 0; r < 4; ++r) {
                    const int row = mt*16 + lq*4 + r;
                    const float v = acc[mt][nn][r];
                    sC[row*SCH + col] = (_Float16)fmaxf(v, 0.2f * v);
                }
            }
    }
    __syncthreads();   // barrier 2: C ready (and all V reads done)

    // -- build P3/P4 B-frags + biases + W4 (consumed after barriers 3/4)
    h8 Bf3[2];
    #pragma unroll
    for (int kq = 0; kq < 2; ++kq)
        Bf3[kq] = bfrag(W2, 32, kq*32 + k8, (wv >> 1)*16 + l15);
    const h8 Bf4 = bfrag(W3, 16, k8, l15);
    const float b2v = b2[(wv >> 1)*16 + l15];
    const float b3v = b3[l15];
    float w4c[3];
    #pragma unroll
    for (int c = 0; c < 3; ++c) w4c[c] = W4[l15*3 + c];

    // ===== Phase 2 (MFMA): H1 = relu(C[32,128] @ W1 + b1) =====
    {
        f4 acc[2];
        #pragma unroll
        for (int mt = 0; mt < 2; ++mt) { f4 z = {b1v,b1v,b1v,b1v}; acc[mt] = z; }
        #pragma unroll
        for (int mt = 0; mt < 2; ++mt)
            #pragma unroll
            for (int kq = 0; kq < 4; ++kq) {
                const h8 Af = *(const h8*)&sC[(mt*16 + l15)*SCH + kq*32 + lq*8];
                acc[mt] = __builtin_amdgcn_mfma_f32_16x16x32_f16(Af, Bf2[kq], acc[mt], 0, 0, 0);
            }
        // epilogue into sV (H1): V reads all completed before barrier 2
        #pragma unroll
        for (int mt = 0; mt < 2; ++mt) {
            const int col = wv*16 + l15;
            #pragma unroll
            for (int r = 0; r < 4; ++r) {
                const int row = mt*16 + lq*4 + r;
                sV[row*S1H + col] = (_Float16)fmaxf(acc[mt][r], 0.f);
            }
        }
    }
    __syncthreads();   // barrier 3: H1 ready (and all C reads done)

    // ===== Phase 3 (MFMA): H2 = relu(H1[32,64] @ W2 + b2) =====
    {
        const int mt = wv & 1;
        const int nt = wv >> 1;
        f4 acc = {b2v, b2v, b2v, b2v};
        #pragma unroll
        for (int kq = 0; kq < 2; ++kq) {
            const h8 Af = *(const h8*)&sV[(mt*16 + l15)*S1H + kq*32 + lq*8];
            acc = __builtin_amdgcn_mfma_f32_16x16x32_f16(Af, Bf3[kq], acc, 0, 0, 0);
        }
        // epilogue into sC (H2 region): C reads done before barrier 3
        const int col = nt*16 + l15;
        #pragma unroll
        for (int r = 0; r < 4; ++r) {
            const int row = mt*16 + lq*4 + r;
            sC[row*S2H + col] = (_Float16)fmaxf(acc[r], 0.f);
        }
    }
    __syncthreads();   // barrier 4: H2 ready

    // ===== Phase 4+5 fused: H3 = relu(H2 @ W3 + b3); out = H3 @ W4 + b4 =====
    if (wv < 2) {
        f4 acc = {b3v, b3v, b3v, b3v};
        const h8 Af = *(const h8*)&sC[(wv*16 + l15)*S2H + lq*8];
        acc = __builtin_amdgcn_mfma_f32_16x16x32_f16(Af, Bf4, acc, 0, 0, 0);
        #pragma unroll
        for (int r = 0; r < 4; ++r) {
            const float h3 = fmaxf(acc[r], 0.f);    // H3[row][l15], row = wv*16+lq*4+r
            #pragma unroll
            for (int c = 0; c < 3; ++c) {
                float p = h3 * w4c[c];
                p += __shfl_xor(p, 1);
                p += __shfl_xor(p, 2);
                p += __shfl_xor(p, 4);
                p += __shfl_xor(p, 8);
                if (l15 == c) {
                    const int gn = blk*32 + wv*16 + lq*4 + r;
                    out[gn*3 + c] = p + b4[c];
                }
            }
        }
    }
}

extern "C" void kernel_launch(void* const* d_in, const int* in_sizes, int n_in,
                              void* d_out, int out_size, void* d_ws, size_t ws_size,
                              hipStream_t stream)
{
    const float* pgi = (const float*)d_in[0];
    const float* Wl  = (const float*)d_in[1];
    const float* bl  = (const float*)d_in[2];
    const float* Wc  = (const float*)d_in[3];
    const float* bc  = (const float*)d_in[4];
    const float* W1  = (const float*)d_in[5];
    const float* b1  = (const float*)d_in[6];
    const float* W2  = (const float*)d_in[7];
    const float* b2  = (const float*)d_in[8];
    const float* W3  = (const float*)d_in[9];
    const float* b3  = (const float*)d_in[10];
    const float* W4  = (const float*)d_in[11];
    const float* b4  = (const float*)d_in[12];

    hipLaunchKernelGGL(flatnet_fused, dim3(1024), dim3(256), 0, stream,
                       pgi, Wl, bl, Wc, bc, W1, b1, W2, b2, W3, b3, W4, b4,
                       (float*)d_out);
}